// Round 1
// baseline (787.200 us; speedup 1.0000x reference)
//
#include <hip/hip_runtime.h>
#include <math.h>

// Problem constants (B,N,D,H) = (4, 2048, 1024, 64)
constexpr int kB = 4;
constexpr int kN = 2048;
constexpr int kD = 1024;
constexpr int kH = 64;
constexpr int kBN = kB * kN;            // 8192 rows
#define INFF __builtin_inff()

__device__ __forceinline__ void ml_merge(float& m, float& l, float mo, float lo) {
    // merge two online-softmax states (m,l) <- (m,l) + (mo,lo)
    if (mo > m) {
        l = l * __expf(m - mo) + lo;    // if m==-inf: expf(-inf)=0, l was 0
        m = mo;
    } else if (mo != -INFF) {
        l += lo * __expf(mo - m);
    } // mo==-inf: lo must be 0, nothing to add (avoids exp(nan) when both -inf)
}

// ---------------------------------------------------------------------------
// Kernel A: q,k,v = x@W + b   (fp32). 256 blocks x 256 thr, 32 rows/block.
// x row data is wave-uniform (readfirstlane) -> scalar loads; W reads coalesced.
// ---------------------------------------------------------------------------
__global__ __launch_bounds__(256) void qkv_kernel(
        const float* __restrict__ x,
        const float* __restrict__ Wq, const float* __restrict__ bq,
        const float* __restrict__ Wk, const float* __restrict__ bk,
        const float* __restrict__ Wv, const float* __restrict__ bv,
        float* __restrict__ gq, float* __restrict__ gk, float* __restrict__ gv)
{
    const int t = threadIdx.x;
    const int h = t & 63;
    const int rg = __builtin_amdgcn_readfirstlane(t >> 6);   // wave id 0..3
    const int row0 = blockIdx.x * 32 + rg * 8;               // 8 rows per wave
    const float* xrow = x + (size_t)row0 * kD;

    float aq[8] = {}, ak[8] = {}, av[8] = {};
    #pragma unroll 4
    for (int d = 0; d < kD; ++d) {
        float wq = Wq[d * kH + h];
        float wk = Wk[d * kH + h];
        float wv = Wv[d * kH + h];
        #pragma unroll
        for (int r = 0; r < 8; ++r) {
            float xv = xrow[r * kD + d];                     // wave-uniform -> s_load
            aq[r] = fmaf(xv, wq, aq[r]);
            ak[r] = fmaf(xv, wk, ak[r]);
            av[r] = fmaf(xv, wv, av[r]);
        }
    }
    const float vbq = bq[h], vbk = bk[h], vbv = bv[h];
    #pragma unroll
    for (int r = 0; r < 8; ++r) {
        size_t o = (size_t)(row0 + r) * kH + h;
        gq[o] = aq[r] + vbq;
        gk[o] = ak[r] + vbk;
        gv[o] = av[r] + vbv;
    }
}

// ---------------------------------------------------------------------------
// Kernel B: per-row softmax stats m[j], l[j] over i in [j, N), s != 0.
// Grid 512: (ic 0..1 half of i-range) x (bz 0..3) x (jt 0..63, 32 rows each).
// Tile: 32 j x 192 i, per-thread 4x6 register block, stride-68 padded LDS.
// ---------------------------------------------------------------------------
__global__ __launch_bounds__(256) void stats_kernel(
        const float* __restrict__ gq, const float* __restrict__ gk,
        float* __restrict__ m2, float* __restrict__ l2)
{
    __shared__ float qs[32 * 68];
    __shared__ float ks[192 * 68];
    const int t = threadIdx.x;
    const int bid = blockIdx.x;
    const int ic = bid >> 8;            // i-chunk 0/1
    const int rem = bid & 255;
    const int bz = rem >> 6;            // batch
    const int jt = rem & 63;
    const int j0 = jt * 32;
    const int ilo = ic * 1024, ihi = ilo + 1024;

    // stage q rows j0..j0+31 (always in-bounds)
    for (int idx = t; idx < 512; idx += 256) {
        int r = idx >> 4, c4 = idx & 15;
        *(float4*)&qs[r * 68 + c4 * 4] =
            *(const float4*)&gq[((size_t)bz * kN + j0 + r) * kH + c4 * 4];
    }

    const int txi = t & 31;             // i-thread 0..31
    const int tyj = t >> 5;             // j-group 0..7 (4 rows each)
    float mloc[4] = {-INFF, -INFF, -INFF, -INFF};
    float lloc[4] = {0.f, 0.f, 0.f, 0.f};

    if (j0 < ihi) {
        int jstart = (j0 > ilo ? j0 : ilo);
        int istart = (jstart / 192) * 192;
        for (int i0 = istart; i0 < ihi; i0 += 192) {
            __syncthreads();
            for (int idx = t; idx < 3072; idx += 256) {
                int r = idx >> 4, c4 = idx & 15;
                int igr = i0 + r;
                float4 kv = make_float4(0.f, 0.f, 0.f, 0.f);
                if (igr < kN)
                    kv = *(const float4*)&gk[((size_t)bz * kN + igr) * kH + c4 * 4];
                *(float4*)&ks[r * 68 + c4 * 4] = kv;
            }
            __syncthreads();

            float acc[4][6];
            #pragma unroll
            for (int b2 = 0; b2 < 4; ++b2)
                #pragma unroll
                for (int a2 = 0; a2 < 6; ++a2) acc[b2][a2] = 0.f;

            #pragma unroll
            for (int h4 = 0; h4 < 16; ++h4) {
                float4 q4[4], k4[6];
                #pragma unroll
                for (int b2 = 0; b2 < 4; ++b2)
                    q4[b2] = *(const float4*)&qs[(tyj * 4 + b2) * 68 + h4 * 4];
                #pragma unroll
                for (int a2 = 0; a2 < 6; ++a2)
                    k4[a2] = *(const float4*)&ks[(txi + 32 * a2) * 68 + h4 * 4];
                #pragma unroll
                for (int b2 = 0; b2 < 4; ++b2)
                    #pragma unroll
                    for (int a2 = 0; a2 < 6; ++a2) {
                        acc[b2][a2] = fmaf(q4[b2].x, k4[a2].x, acc[b2][a2]);
                        acc[b2][a2] = fmaf(q4[b2].y, k4[a2].y, acc[b2][a2]);
                        acc[b2][a2] = fmaf(q4[b2].z, k4[a2].z, acc[b2][a2]);
                        acc[b2][a2] = fmaf(q4[b2].w, k4[a2].w, acc[b2][a2]);
                    }
            }
            #pragma unroll
            for (int b2 = 0; b2 < 4; ++b2) {
                int jg = j0 + tyj * 4 + b2;
                #pragma unroll
                for (int a2 = 0; a2 < 6; ++a2) {
                    int ig = i0 + txi + 32 * a2;
                    float s = acc[b2][a2];
                    bool valid = (ig >= ilo) && (ig < ihi) && (ig >= jg) && (s != 0.0f);
                    if (valid) {
                        float sc = s * 0.125f;
                        if (sc > mloc[b2]) {
                            lloc[b2] = lloc[b2] * __expf(mloc[b2] - sc) + 1.0f;
                            mloc[b2] = sc;
                        } else {
                            lloc[b2] += __expf(sc - mloc[b2]);
                        }
                    }
                }
            }
        }
    }
    // reduce across the 32 i-threads (within half-wave)
    #pragma unroll
    for (int off = 16; off >= 1; off >>= 1) {
        #pragma unroll
        for (int b2 = 0; b2 < 4; ++b2) {
            float mo = __shfl_xor(mloc[b2], off, 32);
            float lo = __shfl_xor(lloc[b2], off, 32);
            ml_merge(mloc[b2], lloc[b2], mo, lo);
        }
    }
    if (txi == 0) {
        #pragma unroll
        for (int b2 = 0; b2 < 4; ++b2) {
            int rgl = bz * kN + j0 + tyj * 4 + b2;
            m2[ic * kBN + rgl] = mloc[b2];
            l2[ic * kBN + rgl] = lloc[b2];
        }
    }
}

// ---------------------------------------------------------------------------
// Kernel B2: merge the 2 i-chunk partial stats, emit m and 1/l.
// ---------------------------------------------------------------------------
__global__ __launch_bounds__(256) void combine_kernel(
        const float* __restrict__ m2, const float* __restrict__ l2,
        float* __restrict__ mf, float* __restrict__ rlf)
{
    int r = blockIdx.x * 256 + threadIdx.x;   // 0..8191
    float m = m2[r], l = l2[r];
    ml_merge(m, l, m2[kBN + r], l2[kBN + r]);
    mf[r] = m;
    rlf[r] = (l > 0.f) ? 1.0f / l : 0.0f;
}

// ---------------------------------------------------------------------------
// Kernel C: out[i,h] partial = sum_{j in chunk, j<=i} exp(s/8 - m[j])/l[j] * v[j,h]
// Grid 512: (jc 0..3 j-chunk of 512) x (bz 0..3) x (it 0..31, 64 i each).
// Every block writes its full 64x64 partial tile (zeros if no work).
// ---------------------------------------------------------------------------
__global__ __launch_bounds__(256) void out_kernel(
        const float* __restrict__ gq, const float* __restrict__ gk,
        const float* __restrict__ gv, const float* __restrict__ mf,
        const float* __restrict__ rlf, float* __restrict__ part)
{
    __shared__ float ksm[64 * 68];
    __shared__ float qsm[32 * 68];
    __shared__ float vsm[32 * 68];
    __shared__ float psm[32 * 68];
    __shared__ float msm[32];
    __shared__ float rsm[32];

    const int t = threadIdx.x;
    const int bid = blockIdx.x;
    const int jc = bid >> 7;
    const int rem = bid & 127;
    const int bz = rem >> 5;
    const int it = rem & 31;
    const int i0 = it * 64;
    const int jlo = jc * 512;
    const int jhi = (i0 + 64 < jlo + 512) ? (i0 + 64) : (jlo + 512);

    const int h4a = t & 15, ig = t >> 4;     // accum mapping: 4i x 4h per thread
    const int txp = t & 31, typ = t >> 5;    // p-compute mapping: 4j x 2i per thread

    float acc[4][4];
    #pragma unroll
    for (int c = 0; c < 4; ++c)
        #pragma unroll
        for (int e = 0; e < 4; ++e) acc[c][e] = 0.f;

    if (jlo < jhi) {
        // stage k rows i0..i0+63 once
        for (int idx = t; idx < 1024; idx += 256) {
            int r = idx >> 4, c4 = idx & 15;
            *(float4*)&ksm[r * 68 + c4 * 4] =
                *(const float4*)&gk[((size_t)bz * kN + i0 + r) * kH + c4 * 4];
        }
        for (int j0 = jlo; j0 < jhi; j0 += 32) {
            __syncthreads();   // also covers initial k staging
            for (int idx = t; idx < 512; idx += 256) {
                int r = idx >> 4, c4 = idx & 15;
                int jg = j0 + r;
                float4 qv = make_float4(0.f, 0.f, 0.f, 0.f), vv = qv;
                if (jg < kN) {
                    size_t o = ((size_t)bz * kN + jg) * kH + c4 * 4;
                    qv = *(const float4*)&gq[o];
                    vv = *(const float4*)&gv[o];
                }
                *(float4*)&qsm[r * 68 + c4 * 4] = qv;
                *(float4*)&vsm[r * 68 + c4 * 4] = vv;
            }
            if (t < 32) {
                int jg = j0 + t;
                msm[t] = (jg < kN) ? mf[bz * kN + jg] : 0.f;
            } else if (t < 64) {
                int jg = j0 + (t - 32);
                rsm[t - 32] = (jg < kN) ? rlf[bz * kN + jg] : 0.f;
            }
            __syncthreads();

            // recompute scores + p
            float pacc[4][2];
            #pragma unroll
            for (int c = 0; c < 4; ++c) { pacc[c][0] = 0.f; pacc[c][1] = 0.f; }
            #pragma unroll
            for (int h4 = 0; h4 < 16; ++h4) {
                float4 q4[4], k4[2];
                #pragma unroll
                for (int c = 0; c < 4; ++c)
                    q4[c] = *(const float4*)&qsm[(typ * 4 + c) * 68 + h4 * 4];
                #pragma unroll
                for (int a = 0; a < 2; ++a)
                    k4[a] = *(const float4*)&ksm[(txp + 32 * a) * 68 + h4 * 4];
                #pragma unroll
                for (int c = 0; c < 4; ++c)
                    #pragma unroll
                    for (int a = 0; a < 2; ++a) {
                        pacc[c][a] = fmaf(q4[c].x, k4[a].x, pacc[c][a]);
                        pacc[c][a] = fmaf(q4[c].y, k4[a].y, pacc[c][a]);
                        pacc[c][a] = fmaf(q4[c].z, k4[a].z, pacc[c][a]);
                        pacc[c][a] = fmaf(q4[c].w, k4[a].w, pacc[c][a]);
                    }
            }
            #pragma unroll
            for (int c = 0; c < 4; ++c) {
                int jj = typ * 4 + c;
                int jg = j0 + jj;
                #pragma unroll
                for (int a = 0; a < 2; ++a) {
                    int ii = txp + 32 * a;
                    int ig2 = i0 + ii;
                    float s = pacc[c][a];
                    bool valid = (jg < jhi) && (ig2 >= jg) && (s != 0.0f);
                    float p = valid ? __expf(s * 0.125f - msm[jj]) * rsm[jj] : 0.f;
                    psm[jj * 68 + ii] = p;
                }
            }
            __syncthreads();

            // accumulate p^T @ v
            for (int jj = 0; jj < 32; ++jj) {
                float4 p4 = *(const float4*)&psm[jj * 68 + ig * 4];
                float4 v4 = *(const float4*)&vsm[jj * 68 + h4a * 4];
                float pv[4] = {p4.x, p4.y, p4.z, p4.w};
                float vv[4] = {v4.x, v4.y, v4.z, v4.w};
                #pragma unroll
                for (int c = 0; c < 4; ++c)
                    #pragma unroll
                    for (int e = 0; e < 4; ++e)
                        acc[c][e] = fmaf(pv[c], vv[e], acc[c][e]);
            }
        }
    }
    // write partial tile (always, so poisoned ws is fully overwritten)
    size_t base = ((size_t)(jc * 4 + bz) * kN + i0) * kH;
    #pragma unroll
    for (int c = 0; c < 4; ++c) {
        float4 o = make_float4(acc[c][0], acc[c][1], acc[c][2], acc[c][3]);
        *(float4*)&part[base + (size_t)(ig * 4 + c) * kH + h4a * 4] = o;
    }
}

// ---------------------------------------------------------------------------
// Kernel D: out = sum of 4 j-chunk partials.
// ---------------------------------------------------------------------------
__global__ __launch_bounds__(256) void reduce_kernel(
        const float* __restrict__ part, float* __restrict__ out)
{
    int idx = blockIdx.x * 256 + threadIdx.x;     // 0..131071 float4s
    const float4* p = (const float4*)part;
    float4 a = p[idx];
    float4 b = p[idx + 131072];
    float4 c = p[idx + 262144];
    float4 d = p[idx + 393216];
    float4 r;
    r.x = a.x + b.x + c.x + d.x;
    r.y = a.y + b.y + c.y + d.y;
    r.z = a.z + b.z + c.z + d.z;
    r.w = a.w + b.w + c.w + d.w;
    ((float4*)out)[idx] = r;
}

extern "C" void kernel_launch(void* const* d_in, const int* in_sizes, int n_in,
                              void* d_out, int out_size, void* d_ws, size_t ws_size,
                              hipStream_t stream)
{
    const float* x  = (const float*)d_in[0];
    const float* Wq = (const float*)d_in[1];
    const float* bq = (const float*)d_in[2];
    const float* Wk = (const float*)d_in[3];
    const float* bk = (const float*)d_in[4];
    const float* Wv = (const float*)d_in[5];
    const float* bv = (const float*)d_in[6];
    float* out = (float*)d_out;

    float* ws = (float*)d_ws;
    float* gq  = ws;                     // 524288
    float* gk  = gq + 524288;            // 524288
    float* gv  = gk + 524288;            // 524288
    float* m2  = gv + 524288;            // 2*8192
    float* l2  = m2 + 2 * kBN;           // 2*8192
    float* mf  = l2 + 2 * kBN;           // 8192
    float* rlf = mf + kBN;               // 8192
    float* part = rlf + kBN;             // 4*524288  (total ~14.2 MB)

    qkv_kernel<<<256, 256, 0, stream>>>(x, Wq, bq, Wk, bk, Wv, bv, gq, gk, gv);
    stats_kernel<<<512, 256, 0, stream>>>(gq, gk, m2, l2);
    combine_kernel<<<32, 256, 0, stream>>>(m2, l2, mf, rlf);
    out_kernel<<<512, 256, 0, stream>>>(gq, gk, gv, mf, rlf, part);
    reduce_kernel<<<512, 256, 0, stream>>>(part, out);
}

// Round 2
// 145.224 us; speedup vs baseline: 5.4206x; 5.4206x over previous
//
#include <hip/hip_runtime.h>
#include <math.h>

// (B,N,D,H) = (4, 2048, 1024, 64)
constexpr int kN = 2048;
constexpr int kD = 1024;
constexpr int kH = 64;
constexpr int kBN = 4 * kN;             // 8192 rows

typedef __attribute__((ext_vector_type(8))) short bf16x8;
typedef __attribute__((ext_vector_type(4))) short bf16x4;
typedef __attribute__((ext_vector_type(4))) float f32x4;

#define MFMA(a, b, c) __builtin_amdgcn_mfma_f32_16x16x32_bf16(a, b, c, 0, 0, 0)

__device__ __forceinline__ short f2bf(float f) {
    unsigned u = __float_as_uint(f);
    u += 0x7fff + ((u >> 16) & 1);      // round-to-nearest-even
    return (short)(u >> 16);
}

__device__ __forceinline__ void ml_merge(float& m, float& l, float mo, float lo) {
    // branchless; sentinel m0 = -1e30 (acts as -inf for |s/8| <= ~50)
    float mn = fmaxf(m, mo);
    l = l * __expf(m - mn) + lo * __expf(mo - mn);
    m = mn;
}

// ---------------------------------------------------------------------------
// prep: Wt[n][d] = bf16(W*[d][n]) packed q|k|v (192 x 1024), bcat = bq|bk|bv
// ---------------------------------------------------------------------------
__global__ __launch_bounds__(256) void prep_kernel(
        const float* __restrict__ Wq, const float* __restrict__ Wk,
        const float* __restrict__ Wv, const float* __restrict__ bq,
        const float* __restrict__ bk, const float* __restrict__ bv,
        short* __restrict__ Wt, float* __restrict__ bcat)
{
    int tid = blockIdx.x * 256 + threadIdx.x;
    for (int e = tid; e < 192 * kD; e += gridDim.x * 256) {
        int n = e >> 10, d = e & 1023;
        float w = (n < 64) ? Wq[d * 64 + n]
                : (n < 128) ? Wk[d * 64 + (n - 64)]
                : Wv[d * 64 + (n - 128)];
        Wt[e] = f2bf(w);
    }
    if (tid < 192)
        bcat[tid] = (tid < 64) ? bq[tid] : (tid < 128) ? bk[tid - 64] : bv[tid - 128];
}

// ---------------------------------------------------------------------------
// qkv: [8192x1024] @ [1024x192] via bf16 MFMA. Block = 32 rows, grid 256.
// Outputs: gq,gk bf16 row-major [8192][64]; v transposed vt[bz*64+h][2048] bf16.
// ---------------------------------------------------------------------------
__global__ __launch_bounds__(256) void qkv_kernel(
        const float* __restrict__ x, const short* __restrict__ Wt,
        const float* __restrict__ bcat,
        short* __restrict__ gq, short* __restrict__ gk, short* __restrict__ vt)
{
    __shared__ short xs[32 * 72];
    __shared__ short wsm[192 * 72];
    const int t = threadIdx.x;
    const int m0 = blockIdx.x * 32;
    const int w = t >> 6, lane = t & 63;
    const int l15 = lane & 15, q8 = lane >> 4;
    const int msub = w & 1;               // 16-row subtile
    const int nh = w >> 1;                // n-half: 96 cols each

    f32x4 acc[6];
    #pragma unroll
    for (int i = 0; i < 6; ++i) acc[i] = (f32x4){0.f, 0.f, 0.f, 0.f};

    for (int k0 = 0; k0 < kD; k0 += 64) {
        __syncthreads();
        // stage x (fp32 -> bf16): 32 rows x 64 k
        #pragma unroll
        for (int p = 0; p < 2; ++p) {
            int idx = t + p * 256;            // 512 float4 chunks
            int row = idx >> 4, c = idx & 15;
            float4 xv = *(const float4*)&x[(size_t)(m0 + row) * kD + k0 + c * 4];
            bf16x4 pk = {f2bf(xv.x), f2bf(xv.y), f2bf(xv.z), f2bf(xv.w)};
            *(bf16x4*)&xs[row * 72 + c * 4] = pk;
        }
        // stage Wt: 192 rows x 64 k (already bf16)
        #pragma unroll
        for (int p = 0; p < 6; ++p) {
            int idx = t + p * 256;            // 1536 16B chunks
            int row = idx >> 3, c = idx & 7;
            *(bf16x8*)&wsm[row * 72 + c * 8] =
                *(const bf16x8*)&Wt[(size_t)row * kD + k0 + c * 8];
        }
        __syncthreads();

        int arow = 16 * msub + l15;
        bf16x8 a0 = *(const bf16x8*)&xs[arow * 72 + q8 * 8];
        bf16x8 a1 = *(const bf16x8*)&xs[arow * 72 + 32 + q8 * 8];
        #pragma unroll
        for (int nt = 0; nt < 6; ++nt) {
            int brow = 96 * nh + 16 * nt + l15;
            bf16x8 b0 = *(const bf16x8*)&wsm[brow * 72 + q8 * 8];
            bf16x8 b1 = *(const bf16x8*)&wsm[brow * 72 + 32 + q8 * 8];
            acc[nt] = MFMA(a0, b0, acc[nt]);
            acc[nt] = MFMA(a1, b1, acc[nt]);
        }
    }

    // epilogue: add bias, convert, scatter
    #pragma unroll
    for (int nt = 0; nt < 6; ++nt) {
        int nb = 96 * nh + 16 * nt;           // tile base (mult of 16, no straddle)
        int n = nb + l15;
        float bias = bcat[n];
        if (nb < 128) {                       // q or k region
            #pragma unroll
            for (int r = 0; r < 4; ++r) {
                int m = m0 + 16 * msub + q8 * 4 + r;
                short bf = f2bf(acc[nt][r] + bias);
                if (nb < 64) gq[(size_t)m * 64 + n] = bf;
                else         gk[(size_t)m * 64 + (n - 64)] = bf;
            }
        } else {                              // v region -> transposed store
            int h = n - 128;
            int bz = m0 >> 11;
            int jb = (m0 & 2047) + 16 * msub + q8 * 4;
            bf16x4 pk = {f2bf(acc[nt][0] + bias), f2bf(acc[nt][1] + bias),
                         f2bf(acc[nt][2] + bias), f2bf(acc[nt][3] + bias)};
            *(bf16x4*)&vt[((size_t)(bz * 64 + h)) * kN + jb] = pk;
        }
    }
}

// ---------------------------------------------------------------------------
// stats: m[j], l[j] over i in [j,N), s != 0. MFMA scores, branchless online.
// Grid 512: ic(4 x 512-i-chunk) x bz(4) x jt(32 x 64 rows).
// ---------------------------------------------------------------------------
__global__ __launch_bounds__(256) void stats_kernel(
        const short* __restrict__ gq, const short* __restrict__ gk,
        float* __restrict__ m2, float* __restrict__ l2)
{
    __shared__ short qsm[64 * 72];
    __shared__ short ksm[64 * 72];
    const int t = threadIdx.x;
    const int w = t >> 6, lane = t & 63;
    const int l15 = lane & 15, q8 = lane >> 4;
    const int b = blockIdx.x;
    const int ic = b >> 7, rem = b & 127;
    const int bz = rem >> 5, jt = rem & 31;
    const int j0 = jt * 64;
    const int ilo = ic * 512, ihi = ilo + 512;
    const int istart = (j0 > ilo) ? j0 : ilo;

    float mloc[4] = {-1e30f, -1e30f, -1e30f, -1e30f};
    float lloc[4] = {0.f, 0.f, 0.f, 0.f};

    if (istart < ihi) {
        // stage q tile once
        #pragma unroll
        for (int p = 0; p < 2; ++p) {
            int idx = t + p * 256;
            int row = idx >> 3, c = idx & 7;
            *(bf16x8*)&qsm[row * 72 + c * 8] =
                *(const bf16x8*)&gq[(size_t)(bz * kN + j0 + row) * 64 + c * 8];
        }
        for (int i0 = istart; i0 < ihi; i0 += 64) {
            __syncthreads();
            #pragma unroll
            for (int p = 0; p < 2; ++p) {
                int idx = t + p * 256;
                int row = idx >> 3, c = idx & 7;
                *(bf16x8*)&ksm[row * 72 + c * 8] =
                    *(const bf16x8*)&gk[(size_t)(bz * kN + i0 + row) * 64 + c * 8];
            }
            __syncthreads();

            int jrow = 16 * w + l15;
            bf16x8 a0 = *(const bf16x8*)&qsm[jrow * 72 + q8 * 8];
            bf16x8 a1 = *(const bf16x8*)&qsm[jrow * 72 + 32 + q8 * 8];
            #pragma unroll
            for (int it = 0; it < 4; ++it) {
                int irow = 16 * it + l15;
                bf16x8 b0 = *(const bf16x8*)&ksm[irow * 72 + q8 * 8];
                bf16x8 b1 = *(const bf16x8*)&ksm[irow * 72 + 32 + q8 * 8];
                f32x4 s = (f32x4){0.f, 0.f, 0.f, 0.f};
                s = MFMA(a0, b0, s);
                s = MFMA(a1, b1, s);
                int ig = i0 + 16 * it + l15;
                #pragma unroll
                for (int r = 0; r < 4; ++r) {
                    int jg = j0 + 16 * w + q8 * 4 + r;
                    float sv = s[r];
                    bool valid = (ig >= jg) && (sv != 0.0f);
                    float sc = valid ? sv * 0.125f : -1e30f;
                    float mn = fmaxf(mloc[r], sc);
                    float e2 = valid ? __expf(sc - mn) : 0.f;
                    lloc[r] = lloc[r] * __expf(mloc[r] - mn) + e2;
                    mloc[r] = mn;
                }
            }
        }
    }
    // reduce across the 16 lanes holding the same 4 rows
    #pragma unroll
    for (int off = 1; off < 16; off <<= 1) {
        #pragma unroll
        for (int r = 0; r < 4; ++r) {
            float mo = __shfl_xor(mloc[r], off);
            float lo = __shfl_xor(lloc[r], off);
            ml_merge(mloc[r], lloc[r], mo, lo);
        }
    }
    if (l15 == 0) {
        #pragma unroll
        for (int r = 0; r < 4; ++r) {
            int jg = j0 + 16 * w + q8 * 4 + r;
            m2[ic * kBN + bz * kN + jg] = mloc[r];
            l2[ic * kBN + bz * kN + jg] = lloc[r];
        }
    }
}

// ---------------------------------------------------------------------------
// combine: merge 4 i-chunk stats -> mf, rlf
// ---------------------------------------------------------------------------
__global__ __launch_bounds__(256) void combine_kernel(
        const float* __restrict__ m2, const float* __restrict__ l2,
        float* __restrict__ mf, float* __restrict__ rlf)
{
    int r = blockIdx.x * 256 + threadIdx.x;   // 0..8191
    float m = m2[r], l = l2[r];
    #pragma unroll
    for (int c = 1; c < 4; ++c)
        ml_merge(m, l, m2[c * kBN + r], l2[c * kBN + r]);
    mf[r] = m;
    rlf[r] = (l > 0.f) ? 1.0f / l : 0.0f;
}

// ---------------------------------------------------------------------------
// out: partial[i,h] = sum_{j in chunk, j<=i} exp(s/8 - m[j]) * rl[j] * v[j,h]
// Grid 512: jc(4 x 512-j-chunk) x bz(4) x it(32 x 64-i-tile).
// Scores recomputed with bit-identical MFMA tiling as stats.
// ---------------------------------------------------------------------------
__global__ __launch_bounds__(256) void out_kernel(
        const short* __restrict__ gq, const short* __restrict__ gk,
        const short* __restrict__ vt, const float* __restrict__ mf,
        const float* __restrict__ rlf, float* __restrict__ part)
{
    __shared__ short ksm[64 * 72];
    __shared__ short qsm[64 * 72];
    __shared__ short vsm[64 * 72];
    __shared__ short psm[64 * 72];
    __shared__ float msm[64];
    __shared__ float rsm[64];
    const int t = threadIdx.x;
    const int w = t >> 6, lane = t & 63;
    const int l15 = lane & 15, q8 = lane >> 4;
    const int b = blockIdx.x;
    const int jc = b >> 7, rem = b & 127;
    const int bz = rem >> 5, it = rem & 31;
    const int i0 = it * 64;
    const int jlo = jc * 512;
    const int jhi = (jlo + 512 < i0 + 64) ? (jlo + 512) : (i0 + 64);

    f32x4 oacc[4];
    #pragma unroll
    for (int i = 0; i < 4; ++i) oacc[i] = (f32x4){0.f, 0.f, 0.f, 0.f};

    if (jlo < jhi) {
        // stage k rows i0..i0+63 once (B operand of S)
        #pragma unroll
        for (int p = 0; p < 2; ++p) {
            int idx = t + p * 256;
            int row = idx >> 3, c = idx & 7;
            *(bf16x8*)&ksm[row * 72 + c * 8] =
                *(const bf16x8*)&gk[(size_t)(bz * kN + i0 + row) * 64 + c * 8];
        }
        for (int j0s = jlo; j0s < jhi; j0s += 64) {
            __syncthreads();  // ksm ready; qsm/vsm/psm safe to overwrite
            #pragma unroll
            for (int p = 0; p < 2; ++p) {
                int idx = t + p * 256;
                int row = idx >> 3, c = idx & 7;
                *(bf16x8*)&qsm[row * 72 + c * 8] =
                    *(const bf16x8*)&gq[(size_t)(bz * kN + j0s + row) * 64 + c * 8];
                *(bf16x8*)&vsm[row * 72 + c * 8] =
                    *(const bf16x8*)&vt[(size_t)(bz * 64 + row) * kN + j0s + c * 8];
            }
            if (t < 64) msm[t] = mf[bz * kN + j0s + t];
            else if (t < 128) rsm[t - 64] = rlf[bz * kN + j0s + (t - 64)];
            __syncthreads();

            // S phase: wave w = j-subtile (same tiling as stats -> identical s)
            int jrow = 16 * w + l15;
            bf16x8 a0 = *(const bf16x8*)&qsm[jrow * 72 + q8 * 8];
            bf16x8 a1 = *(const bf16x8*)&qsm[jrow * 72 + 32 + q8 * 8];
            #pragma unroll
            for (int itile = 0; itile < 4; ++itile) {
                int irow = 16 * itile + l15;
                bf16x8 b0 = *(const bf16x8*)&ksm[irow * 72 + q8 * 8];
                bf16x8 b1 = *(const bf16x8*)&ksm[irow * 72 + 32 + q8 * 8];
                f32x4 s = (f32x4){0.f, 0.f, 0.f, 0.f};
                s = MFMA(a0, b0, s);
                s = MFMA(a1, b1, s);
                int ig = i0 + 16 * itile + l15;
                bf16x4 pk;
                #pragma unroll
                for (int r = 0; r < 4; ++r) {
                    int jl = 16 * w + q8 * 4 + r;
                    int jg = j0s + jl;
                    float sv = s[r];
                    bool valid = (ig >= jg) && (sv != 0.0f);
                    float p = valid ? __expf(sv * 0.125f - msm[jl]) * rsm[jl] : 0.f;
                    pk[r] = f2bf(p);
                }
                *(bf16x4*)&psm[(16 * itile + l15) * 72 + 16 * w + q8 * 4] = pk;
            }
            __syncthreads();

            // PV phase: wave w = i-subtile; A = psm (P^T), B = vsm (V^T rows h)
            int prow = 16 * w + l15;
            bf16x8 pa0 = *(const bf16x8*)&psm[prow * 72 + q8 * 8];
            bf16x8 pa1 = *(const bf16x8*)&psm[prow * 72 + 32 + q8 * 8];
            #pragma unroll
            for (int ht = 0; ht < 4; ++ht) {
                int vrow = 16 * ht + l15;
                bf16x8 vb0 = *(const bf16x8*)&vsm[vrow * 72 + q8 * 8];
                bf16x8 vb1 = *(const bf16x8*)&vsm[vrow * 72 + 32 + q8 * 8];
                oacc[ht] = MFMA(pa0, vb0, oacc[ht]);
                oacc[ht] = MFMA(pa1, vb1, oacc[ht]);
            }
        }
    }
    // write partial tile (always: poisoned ws must be overwritten)
    size_t base = ((size_t)(jc * 4 + bz) * kN + i0) * 64;
    #pragma unroll
    for (int ht = 0; ht < 4; ++ht)
        #pragma unroll
        for (int r = 0; r < 4; ++r)
            part[base + (size_t)(16 * w + q8 * 4 + r) * 64 + 16 * ht + l15] = oacc[ht][r];
}

// ---------------------------------------------------------------------------
// reduce: out = sum of 4 j-chunk partials
// ---------------------------------------------------------------------------
__global__ __launch_bounds__(256) void reduce_kernel(
        const float* __restrict__ part, float* __restrict__ out)
{
    int idx = blockIdx.x * 256 + threadIdx.x;     // 0..131071 float4s
    const float4* p = (const float4*)part;
    float4 a = p[idx];
    float4 b = p[idx + 131072];
    float4 c = p[idx + 262144];
    float4 d = p[idx + 393216];
    float4 r;
    r.x = a.x + b.x + c.x + d.x;
    r.y = a.y + b.y + c.y + d.y;
    r.z = a.z + b.z + c.z + d.z;
    r.w = a.w + b.w + c.w + d.w;
    ((float4*)out)[idx] = r;
}

extern "C" void kernel_launch(void* const* d_in, const int* in_sizes, int n_in,
                              void* d_out, int out_size, void* d_ws, size_t ws_size,
                              hipStream_t stream)
{
    const float* x  = (const float*)d_in[0];
    const float* Wq = (const float*)d_in[1];
    const float* bq = (const float*)d_in[2];
    const float* Wk = (const float*)d_in[3];
    const float* bk = (const float*)d_in[4];
    const float* Wv = (const float*)d_in[5];
    const float* bv = (const float*)d_in[6];
    float* out = (float*)d_out;

    char* base = (char*)d_ws;
    short* Wt   = (short*)base;                      // 393,216 B
    float* bcat = (float*)(base + 393216);           // 1,024 B (padded)
    short* gq   = (short*)(base + 394240);           // 1,048,576 B
    short* gk   = (short*)(base + 1442816);          // 1,048,576 B
    short* vt   = (short*)(base + 2491392);          // 1,048,576 B
    float* m2   = (float*)(base + 3539968);          // 131,072 B (4 chunks)
    float* l2   = (float*)(base + 3671040);          // 131,072 B
    float* mf   = (float*)(base + 3802112);          // 32,768 B
    float* rlf  = (float*)(base + 3834880);          // 32,768 B
    float* part = (float*)(base + 3867648);          // 8,388,608 B  (~12.2 MB total)

    prep_kernel<<<96, 256, 0, stream>>>(Wq, Wk, Wv, bq, bk, bv, Wt, bcat);
    qkv_kernel<<<256, 256, 0, stream>>>(x, Wt, bcat, gq, gk, vt);
    stats_kernel<<<512, 256, 0, stream>>>(gq, gk, m2, l2);
    combine_kernel<<<32, 256, 0, stream>>>(m2, l2, mf, rlf);
    out_kernel<<<512, 256, 0, stream>>>(gq, gk, vt, mf, rlf, part);
    reduce_kernel<<<512, 256, 0, stream>>>(part, out);
}

// Round 3
// 143.144 us; speedup vs baseline: 5.4994x; 1.0145x over previous
//
#include <hip/hip_runtime.h>
#include <math.h>

// (B,N,D,H) = (4, 2048, 1024, 64)
constexpr int kN = 2048;
constexpr int kD = 1024;

typedef __attribute__((ext_vector_type(8))) short bf16x8;
typedef __attribute__((ext_vector_type(4))) short bf16x4;
typedef __attribute__((ext_vector_type(4))) float f32x4;

#define MFMA(a, b, c) __builtin_amdgcn_mfma_f32_16x16x32_bf16(a, b, c, 0, 0, 0)

__device__ __forceinline__ short f2bf(float f) {
    unsigned u = __float_as_uint(f);
    u += 0x7fff + ((u >> 16) & 1);      // round-to-nearest-even
    return (short)(u >> 16);
}

// global->LDS direct DMA. LDS dest = wave-uniform base + lane*16.
// Copies nbytes (contiguous in both spaces) with 256 threads.
__device__ __forceinline__ void g2l(void* lds, const void* g, int nbytes, int t) {
    int lane = t & 63, w = t >> 6;
    for (int base = w * 1024; base < nbytes; base += 4096) {
        if (base + lane * 16 < nbytes) {
            __builtin_amdgcn_global_load_lds(
                (const __attribute__((address_space(1))) void*)((const char*)g + base + lane * 16),
                (__attribute__((address_space(3))) void*)((char*)lds + base),
                16, 0, 0);
        }
    }
}

// ---------------------------------------------------------------------------
// prep: xb_tiled[kc][8192][72] = bf16(x), Wt_tiled[kc][192][72] = bf16(W^T),
// bcat = bq|bk|bv. Pitch-72 (144B) padded rows -> contiguous g2l-able tiles.
// ---------------------------------------------------------------------------
__global__ __launch_bounds__(256) void prep_kernel(
        const float* __restrict__ x,
        const float* __restrict__ Wq, const float* __restrict__ Wk,
        const float* __restrict__ Wv, const float* __restrict__ bq,
        const float* __restrict__ bk, const float* __restrict__ bv,
        short* __restrict__ xb, short* __restrict__ Wt, float* __restrict__ bcat)
{
    int tid = blockIdx.x * 256 + threadIdx.x;
    int stride = gridDim.x * 256;
    // x: 16*8192*64 elements, c fastest (coalesced read + write)
    for (int e = tid; e < 16 * 8192 * 64; e += stride) {
        int kc = e >> 19;
        int rem = e & 524287;
        int row = rem >> 6, c = rem & 63;
        xb[((size_t)(kc * 8192 + row)) * 72 + c] = f2bf(x[(size_t)row * kD + kc * 64 + c]);
    }
    // W: n fastest for coalesced reads of W[d][n]
    for (int e = tid; e < 16 * 64 * 192; e += stride) {
        int n = e % 192;
        int rc = e / 192;
        int c = rc & 63, kc = rc >> 6;
        int d = kc * 64 + c;
        float wv = (n < 64) ? Wq[d * 64 + n]
                 : (n < 128) ? Wk[d * 64 + (n - 64)]
                 : Wv[d * 64 + (n - 128)];
        Wt[(kc * 192 + n) * 72 + c] = f2bf(wv);
    }
    if (tid < 192)
        bcat[tid] = (tid < 64) ? bq[tid] : (tid < 128) ? bk[tid - 64] : bv[tid - 128];
}

// ---------------------------------------------------------------------------
// qkv: [8192x1024]@[1024x192] bf16 MFMA. 256 blocks x 32 rows. Wave = 32x48
// (R2 x C3 16-tiles). All staging via global_load_lds.
// Outputs padded: gq/gk[8192][72], vt tiled [bz*32+jt][64h][72] (j-local cols).
// ---------------------------------------------------------------------------
__global__ __launch_bounds__(256) void qkv_kernel(
        const short* __restrict__ xb, const short* __restrict__ Wt,
        const float* __restrict__ bcat,
        short* __restrict__ gq, short* __restrict__ gk, short* __restrict__ vt)
{
    __shared__ __align__(16) short xs[32 * 72];
    __shared__ __align__(16) short wsm[192 * 72];
    const int t = threadIdx.x;
    const int w = t >> 6, lane = t & 63, l15 = lane & 15, q8 = lane >> 4;
    const int m0 = blockIdx.x * 32;

    f32x4 acc[2][3];
    #pragma unroll
    for (int rt = 0; rt < 2; ++rt)
        #pragma unroll
        for (int ct = 0; ct < 3; ++ct) acc[rt][ct] = (f32x4){0.f, 0.f, 0.f, 0.f};

    for (int kc = 0; kc < 16; ++kc) {
        __syncthreads();
        g2l(xs, xb + ((size_t)(kc * 8192 + m0)) * 72, 32 * 144, t);
        g2l(wsm, Wt + (size_t)kc * 192 * 72, 192 * 144, t);
        __syncthreads();

        bf16x8 a[2][2], b[3][2];
        #pragma unroll
        for (int rt = 0; rt < 2; ++rt) {
            int arow = rt * 16 + l15;
            a[rt][0] = *(const bf16x8*)&xs[arow * 72 + q8 * 8];
            a[rt][1] = *(const bf16x8*)&xs[arow * 72 + 32 + q8 * 8];
        }
        #pragma unroll
        for (int ct = 0; ct < 3; ++ct) {
            int brow = w * 48 + ct * 16 + l15;
            b[ct][0] = *(const bf16x8*)&wsm[brow * 72 + q8 * 8];
            b[ct][1] = *(const bf16x8*)&wsm[brow * 72 + 32 + q8 * 8];
        }
        #pragma unroll
        for (int rt = 0; rt < 2; ++rt)
            #pragma unroll
            for (int ct = 0; ct < 3; ++ct) {
                acc[rt][ct] = MFMA(a[rt][0], b[ct][0], acc[rt][ct]);
                acc[rt][ct] = MFMA(a[rt][1], b[ct][1], acc[rt][ct]);
            }
    }

    const int bz = m0 >> 11;
    const int jt = (m0 & 2047) >> 6;
    const int jb = m0 & 63;                    // 0 or 32
    #pragma unroll
    for (int rt = 0; rt < 2; ++rt)
        #pragma unroll
        for (int ct = 0; ct < 3; ++ct) {
            int nb = w * 48 + ct * 16;         // 16-tile fits one region
            int n = nb + l15;
            float bias = bcat[n];
            if (nb < 64) {
                #pragma unroll
                for (int r = 0; r < 4; ++r)
                    gq[(size_t)(m0 + rt * 16 + q8 * 4 + r) * 72 + n] =
                        f2bf(acc[rt][ct][r] + bias);
            } else if (nb < 128) {
                #pragma unroll
                for (int r = 0; r < 4; ++r)
                    gk[(size_t)(m0 + rt * 16 + q8 * 4 + r) * 72 + (n - 64)] =
                        f2bf(acc[rt][ct][r] + bias);
            } else {
                int h = n - 128;
                bf16x4 pk = {f2bf(acc[rt][ct][0] + bias), f2bf(acc[rt][ct][1] + bias),
                             f2bf(acc[rt][ct][2] + bias), f2bf(acc[rt][ct][3] + bias)};
                *(bf16x4*)&vt[((size_t)((bz * 32 + jt) * 64 + h)) * 72 + jb + rt * 16 + q8 * 4] = pk;
            }
        }
}

// ---------------------------------------------------------------------------
// stats: l[j] = sum_{i>=j, s!=0} exp(s/8).  No max subtraction (|s/8| <= ~6).
// Grid 512: b&3 = i-chunk (512 wide), (b>>2)&3 = bz, b>>4 = j-tile (64 rows).
// ---------------------------------------------------------------------------
__global__ __launch_bounds__(256) void stats_kernel(
        const short* __restrict__ gq, const short* __restrict__ gk,
        float* __restrict__ l2)
{
    __shared__ __align__(16) short qsm[64 * 72];
    __shared__ __align__(16) short ksm[64 * 72];
    const int t = threadIdx.x;
    const int w = t >> 6, lane = t & 63, l15 = lane & 15, q8 = lane >> 4;
    const int b = blockIdx.x;
    const int ic = b & 3, bz = (b >> 2) & 3, jt = b >> 4;
    const int j0 = jt * 64;
    const int ilo = ic * 512, ihi = ilo + 512;
    const int istart = (j0 > ilo) ? j0 : ilo;

    float lloc[4] = {0.f, 0.f, 0.f, 0.f};

    if (istart < ihi) {                        // block-uniform
        g2l(qsm, gq + (size_t)(bz * kN + j0) * 72, 64 * 144, t);
        __syncthreads();
        int jrow = 16 * w + l15;
        bf16x8 a0 = *(const bf16x8*)&qsm[jrow * 72 + q8 * 8];
        bf16x8 a1 = *(const bf16x8*)&qsm[jrow * 72 + 32 + q8 * 8];

        for (int i0 = istart; i0 < ihi; i0 += 64) {
            __syncthreads();
            g2l(ksm, gk + (size_t)(bz * kN + i0) * 72, 64 * 144, t);
            __syncthreads();
            #pragma unroll
            for (int it = 0; it < 4; ++it) {
                int irow = it * 16 + l15;
                bf16x8 b0 = *(const bf16x8*)&ksm[irow * 72 + q8 * 8];
                bf16x8 b1 = *(const bf16x8*)&ksm[irow * 72 + 32 + q8 * 8];
                f32x4 s = (f32x4){0.f, 0.f, 0.f, 0.f};
                s = MFMA(a0, b0, s);
                s = MFMA(a1, b1, s);
                int ig = i0 + it * 16 + l15;
                #pragma unroll
                for (int r = 0; r < 4; ++r) {
                    int jg = j0 + 16 * w + q8 * 4 + r;
                    float sv = s[r];
                    float e = __expf(sv * 0.125f);
                    lloc[r] += ((ig >= jg) && (sv != 0.0f)) ? e : 0.0f;
                }
            }
        }
    }
    #pragma unroll
    for (int off = 1; off < 16; off <<= 1)
        #pragma unroll
        for (int r = 0; r < 4; ++r)
            lloc[r] += __shfl_xor(lloc[r], off);
    if (l15 == 0) {
        #pragma unroll
        for (int r = 0; r < 4; ++r)
            l2[ic * 8192 + bz * kN + j0 + 16 * w + q8 * 4 + r] = lloc[r];
    }
}

// ---------------------------------------------------------------------------
// combine: rlf = 1 / sum of 4 chunk partials
// ---------------------------------------------------------------------------
__global__ __launch_bounds__(256) void combine_kernel(
        const float* __restrict__ l2, float* __restrict__ rlf)
{
    int r = blockIdx.x * 256 + threadIdx.x;
    float l = l2[r] + l2[8192 + r] + l2[16384 + r] + l2[24576 + r];
    rlf[r] = (l > 0.f) ? 1.0f / l : 0.0f;
}

// ---------------------------------------------------------------------------
// out: partial[i,h] = sum_{j in chunk, j<=i} exp(s/8)*rl[j]*v[j,h]
// Grid 512: b&3 = j-chunk(512), (b>>2)&3 = bz, b>>4 = i-tile(64).
// S recomputed with bit-identical MFMA sequence as stats.
// ---------------------------------------------------------------------------
__global__ __launch_bounds__(256) void out_kernel(
        const short* __restrict__ gq, const short* __restrict__ gk,
        const short* __restrict__ vt, const float* __restrict__ rlf,
        float* __restrict__ part)
{
    __shared__ __align__(16) short ksm[64 * 72];
    __shared__ __align__(16) short qsm[64 * 72];
    __shared__ __align__(16) short vsm[64 * 72];
    __shared__ __align__(16) short psm[64 * 72];
    __shared__ float rsm[64];
    const int t = threadIdx.x;
    const int w = t >> 6, lane = t & 63, l15 = lane & 15, q8 = lane >> 4;
    const int b = blockIdx.x;
    const int jc = b & 3, bz = (b >> 2) & 3, it = b >> 4;
    const int i0 = it * 64;
    const int jlo = jc * 512;
    const int jhi = (jlo + 512 < i0 + 64) ? (jlo + 512) : (i0 + 64);

    f32x4 oacc[4];
    #pragma unroll
    for (int i = 0; i < 4; ++i) oacc[i] = (f32x4){0.f, 0.f, 0.f, 0.f};

    if (jlo < jhi) {                           // block-uniform
        g2l(ksm, gk + (size_t)(bz * kN + i0) * 72, 64 * 144, t);
        for (int j0s = jlo; j0s < jhi; j0s += 64) {
            __syncthreads();                   // prev-iter reads done
            g2l(qsm, gq + (size_t)(bz * kN + j0s) * 72, 64 * 144, t);
            g2l(vsm, vt + (size_t)((bz * 32 + (j0s >> 6)) * 64) * 72, 64 * 144, t);
            if (t < 64) rsm[t] = rlf[bz * kN + j0s + t];
            __syncthreads();                   // staging visible (vmcnt drained)

            // S phase (identical sequence to stats)
            int jrow = 16 * w + l15;
            bf16x8 a0 = *(const bf16x8*)&qsm[jrow * 72 + q8 * 8];
            bf16x8 a1 = *(const bf16x8*)&qsm[jrow * 72 + 32 + q8 * 8];
            #pragma unroll
            for (int itile = 0; itile < 4; ++itile) {
                int irow = itile * 16 + l15;
                bf16x8 b0 = *(const bf16x8*)&ksm[irow * 72 + q8 * 8];
                bf16x8 b1 = *(const bf16x8*)&ksm[irow * 72 + 32 + q8 * 8];
                f32x4 s = (f32x4){0.f, 0.f, 0.f, 0.f};
                s = MFMA(a0, b0, s);
                s = MFMA(a1, b1, s);
                int ig = i0 + itile * 16 + l15;
                bf16x4 pk;
                #pragma unroll
                for (int r = 0; r < 4; ++r) {
                    int jl = 16 * w + q8 * 4 + r;
                    int jg = j0s + jl;
                    float sv = s[r];
                    float p = ((ig >= jg) && (sv != 0.0f))
                            ? __expf(sv * 0.125f) * rsm[jl] : 0.0f;
                    pk[r] = f2bf(p);
                }
                *(bf16x4*)&psm[(itile * 16 + l15) * 72 + 16 * w + q8 * 4] = pk;
            }
            __syncthreads();

            // PV phase: A = psm[i-local][j], B = vsm[h][j]
            bf16x8 pa0 = *(const bf16x8*)&psm[(16 * w + l15) * 72 + q8 * 8];
            bf16x8 pa1 = *(const bf16x8*)&psm[(16 * w + l15) * 72 + 32 + q8 * 8];
            #pragma unroll
            for (int ht = 0; ht < 4; ++ht) {
                int vrow = ht * 16 + l15;
                bf16x8 vb0 = *(const bf16x8*)&vsm[vrow * 72 + q8 * 8];
                bf16x8 vb1 = *(const bf16x8*)&vsm[vrow * 72 + 32 + q8 * 8];
                oacc[ht] = MFMA(pa0, vb0, oacc[ht]);
                oacc[ht] = MFMA(pa1, vb1, oacc[ht]);
            }
        }
    }
    size_t base = ((size_t)(jc * 4 + bz) * kN + i0) * 64;
    #pragma unroll
    for (int ht = 0; ht < 4; ++ht)
        #pragma unroll
        for (int r = 0; r < 4; ++r)
            part[base + (size_t)(16 * w + q8 * 4 + r) * 64 + ht * 16 + l15] = oacc[ht][r];
}

// ---------------------------------------------------------------------------
// reduce: out = sum of 4 j-chunk partials
// ---------------------------------------------------------------------------
__global__ __launch_bounds__(256) void reduce_kernel(
        const float* __restrict__ part, float* __restrict__ out)
{
    int idx = blockIdx.x * 256 + threadIdx.x;     // 0..131071 float4s
    const float4* p = (const float4*)part;
    float4 a = p[idx];
    float4 b = p[idx + 131072];
    float4 c = p[idx + 262144];
    float4 d = p[idx + 393216];
    float4 r;
    r.x = a.x + b.x + c.x + d.x;
    r.y = a.y + b.y + c.y + d.y;
    r.z = a.z + b.z + c.z + d.z;
    r.w = a.w + b.w + c.w + d.w;
    ((float4*)out)[idx] = r;
}

extern "C" void kernel_launch(void* const* d_in, const int* in_sizes, int n_in,
                              void* d_out, int out_size, void* d_ws, size_t ws_size,
                              hipStream_t stream)
{
    const float* x  = (const float*)d_in[0];
    const float* Wq = (const float*)d_in[1];
    const float* bq = (const float*)d_in[2];
    const float* Wk = (const float*)d_in[3];
    const float* bk = (const float*)d_in[4];
    const float* Wv = (const float*)d_in[5];
    const float* bv = (const float*)d_in[6];
    float* out = (float*)d_out;

    char* base = (char*)d_ws;
    short* Wt   = (short*)(base);                    //    442,368 B
    float* bcat = (float*)(base + 442368);           //      1,024 B
    short* xb   = (short*)(base + 443392);           // 18,874,368 B
    short* gq   = (short*)(base + 19317760);         //  1,179,648 B
    short* gk   = (short*)(base + 20497408);         //  1,179,648 B
    short* vt   = (short*)(base + 21677056);         //  1,179,648 B
    float* l2   = (float*)(base + 22856704);         //    131,072 B
    float* rlf  = (float*)(base + 22987776);         //     32,768 B
    float* part = (float*)(base + 23020544);         //  8,388,608 B (total ~31.4 MB)

    prep_kernel<<<2048, 256, 0, stream>>>(x, Wq, Wk, Wv, bq, bk, bv, xb, Wt, bcat);
    qkv_kernel<<<256, 256, 0, stream>>>(xb, Wt, bcat, gq, gk, vt);
    stats_kernel<<<512, 256, 0, stream>>>(gq, gk, l2);
    combine_kernel<<<32, 256, 0, stream>>>(l2, rlf);
    out_kernel<<<512, 256, 0, stream>>>(gq, gk, vt, rlf, part);
    reduce_kernel<<<512, 256, 0, stream>>>(part, out);
}

// Round 4
// 134.864 us; speedup vs baseline: 5.8370x; 1.0614x over previous
//
#include <hip/hip_runtime.h>
#include <math.h>

// (B,N,D,H) = (4, 2048, 1024, 64)
constexpr int kN = 2048;
constexpr int kD = 1024;

typedef __attribute__((ext_vector_type(8))) short bf16x8;
typedef __attribute__((ext_vector_type(4))) short bf16x4;
typedef __attribute__((ext_vector_type(4))) float f32x4;

#define MFMA(a, b, c) __builtin_amdgcn_mfma_f32_16x16x32_bf16(a, b, c, 0, 0, 0)

__device__ __forceinline__ short f2bf(float f) {
    unsigned u = __float_as_uint(f);
    u += 0x7fff + ((u >> 16) & 1);      // round-to-nearest-even
    return (short)(u >> 16);
}

// global->LDS direct DMA. LDS dest = wave-uniform base + lane*16.
__device__ __forceinline__ void g2l(void* lds, const void* g, int nbytes, int t) {
    int lane = t & 63, w = t >> 6;
    for (int base = w * 1024; base < nbytes; base += 4096) {
        if (base + lane * 16 < nbytes) {
            __builtin_amdgcn_global_load_lds(
                (const __attribute__((address_space(1))) void*)((const char*)g + base + lane * 16),
                (__attribute__((address_space(3))) void*)((char*)lds + base),
                16, 0, 0);
        }
    }
}

// ---------------------------------------------------------------------------
// prep: Wt[kc][192][72] = bf16(W^T) (pitch-72 g2l-ready tiles), bcat = bq|bk|bv
// ---------------------------------------------------------------------------
__global__ __launch_bounds__(256) void prep_kernel(
        const float* __restrict__ Wq, const float* __restrict__ Wk,
        const float* __restrict__ Wv, const float* __restrict__ bq,
        const float* __restrict__ bk, const float* __restrict__ bv,
        short* __restrict__ Wt, float* __restrict__ bcat)
{
    int tid = blockIdx.x * 256 + threadIdx.x;
    int stride = gridDim.x * 256;
    for (int e = tid; e < 16 * 192 * 72; e += stride) {
        int kc = e / (192 * 72);
        int rem = e - kc * (192 * 72);
        int n = rem / 72, c = rem - n * 72;
        short v = 0;
        if (c < 64) {
            int d = kc * 64 + c;
            float wv = (n < 64) ? Wq[d * 64 + n]
                     : (n < 128) ? Wk[d * 64 + (n - 64)]
                     : Wv[d * 64 + (n - 128)];
            v = f2bf(wv);
        }
        Wt[e] = v;
    }
    if (tid < 192)
        bcat[tid] = (tid < 64) ? bq[tid] : (tid < 128) ? bk[tid - 64] : bv[tid - 128];
}

// ---------------------------------------------------------------------------
// qkv: [8192x1024]@[1024x192]. 512 blocks x 16 rows. Wave w = cols [48w,48w+48).
// x loaded fp32 direct (prefetch 2 deep), W via double-buffered g2l.
// Outputs: gq/gk[8192][72] bf16, vt[(bz*32+jt)*64+h][72] bf16 (j-local cols).
// ---------------------------------------------------------------------------
__global__ __launch_bounds__(256) void qkv_kernel(
        const float* __restrict__ x, const short* __restrict__ Wt,
        const float* __restrict__ bcat,
        short* __restrict__ gq, short* __restrict__ gk, short* __restrict__ vt)
{
    __shared__ __align__(16) short xs[2][16 * 72];
    __shared__ __align__(16) short wsm[2][192 * 72];
    const int t = threadIdx.x;
    const int w = t >> 6, lane = t & 63, l15 = lane & 15, q8 = lane >> 4;
    const int m0 = blockIdx.x * 16;
    const int xrow = t >> 4, xc4 = t & 15;            // x stage mapping
    const float* xbase = x + (size_t)(m0 + xrow) * kD + xc4 * 4;

    f32x4 acc[3];
    #pragma unroll
    for (int ct = 0; ct < 3; ++ct) acc[ct] = (f32x4){0.f, 0.f, 0.f, 0.f};

    // prologue: kc=0 staged, kc=1 x in flight
    float4 xcur = *(const float4*)(xbase + 0 * 64);
    g2l(wsm[0], Wt, 192 * 144, t);
    {
        bf16x4 pk = {f2bf(xcur.x), f2bf(xcur.y), f2bf(xcur.z), f2bf(xcur.w)};
        *(bf16x4*)&xs[0][xrow * 72 + xc4 * 4] = pk;
    }
    float4 xnxt = *(const float4*)(xbase + 1 * 64);
    __syncthreads();

    for (int kc = 0; kc < 16; ++kc) {
        const int cur = kc & 1, nb = cur ^ 1;
        if (kc < 15)
            g2l(wsm[nb], Wt + (size_t)(kc + 1) * 192 * 72, 192 * 144, t);

        bf16x8 a0 = *(const bf16x8*)&xs[cur][l15 * 72 + q8 * 8];
        bf16x8 a1 = *(const bf16x8*)&xs[cur][l15 * 72 + 32 + q8 * 8];
        #pragma unroll
        for (int ct = 0; ct < 3; ++ct) {
            int brow = w * 48 + ct * 16 + l15;
            bf16x8 b0 = *(const bf16x8*)&wsm[cur][brow * 72 + q8 * 8];
            bf16x8 b1 = *(const bf16x8*)&wsm[cur][brow * 72 + 32 + q8 * 8];
            acc[ct] = MFMA(a0, b0, acc[ct]);
            acc[ct] = MFMA(a1, b1, acc[ct]);
        }
        if (kc < 15) {
            bf16x4 pk = {f2bf(xnxt.x), f2bf(xnxt.y), f2bf(xnxt.z), f2bf(xnxt.w)};
            *(bf16x4*)&xs[nb][xrow * 72 + xc4 * 4] = pk;
            if (kc < 14)
                xnxt = *(const float4*)(xbase + (kc + 2) * 64);
        }
        __syncthreads();
    }

    const int bz = m0 >> 11;
    const int jt = (m0 & 2047) >> 6;
    const int jb = m0 & 63;                // 0/16/32/48
    #pragma unroll
    for (int ct = 0; ct < 3; ++ct) {
        int nb2 = w * 48 + ct * 16;        // 16-tile lies in one region
        int n = nb2 + l15;
        float bias = bcat[n];
        if (nb2 < 64) {
            #pragma unroll
            for (int r = 0; r < 4; ++r)
                gq[(size_t)(m0 + q8 * 4 + r) * 72 + n] = f2bf(acc[ct][r] + bias);
        } else if (nb2 < 128) {
            #pragma unroll
            for (int r = 0; r < 4; ++r)
                gk[(size_t)(m0 + q8 * 4 + r) * 72 + (n - 64)] = f2bf(acc[ct][r] + bias);
        } else {
            int h = n - 128;
            bf16x4 pk = {f2bf(acc[ct][0] + bias), f2bf(acc[ct][1] + bias),
                         f2bf(acc[ct][2] + bias), f2bf(acc[ct][3] + bias)};
            *(bf16x4*)&vt[((size_t)((bz * 32 + jt) * 64 + h)) * 72 + jb + q8 * 4] = pk;
        }
    }
}

// ---------------------------------------------------------------------------
// stats: l[j] = sum_{i>=j, s!=0} exp(s/8). Double-buffered k tiles.
// Grid 512: b&3 = i-chunk(512), (b>>2)&3 = bz, b>>4 = j-tile(64).
// ---------------------------------------------------------------------------
__global__ __launch_bounds__(256) void stats_kernel(
        const short* __restrict__ gq, const short* __restrict__ gk,
        float* __restrict__ l2)
{
    __shared__ __align__(16) short qsm[64 * 72];
    __shared__ __align__(16) short ksm[2][64 * 72];
    const int t = threadIdx.x;
    const int w = t >> 6, lane = t & 63, l15 = lane & 15, q8 = lane >> 4;
    const int b = blockIdx.x;
    const int ic = b & 3, bz = (b >> 2) & 3, jt = b >> 4;
    const int j0 = jt * 64;
    const int ilo = ic * 512, ihi = ilo + 512;
    const int istart = (j0 > ilo) ? j0 : ilo;
    const int count = (istart < ihi) ? ((ihi - istart) >> 6) : 0;

    float lloc[4] = {0.f, 0.f, 0.f, 0.f};

    if (count > 0) {
        g2l(qsm, gq + (size_t)(bz * kN + j0) * 72, 64 * 144, t);
        g2l(ksm[0], gk + (size_t)(bz * kN + istart) * 72, 64 * 144, t);
        __syncthreads();
        int jrow = 16 * w + l15;
        bf16x8 a0 = *(const bf16x8*)&qsm[jrow * 72 + q8 * 8];
        bf16x8 a1 = *(const bf16x8*)&qsm[jrow * 72 + 32 + q8 * 8];

        for (int idx = 0; idx < count; ++idx) {
            const int cur = idx & 1;
            if (idx + 1 < count)
                g2l(ksm[cur ^ 1],
                    gk + (size_t)(bz * kN + istart + (idx + 1) * 64) * 72, 64 * 144, t);
            const int i0 = istart + idx * 64;
            #pragma unroll
            for (int it = 0; it < 4; ++it) {
                int irow = it * 16 + l15;
                bf16x8 b0 = *(const bf16x8*)&ksm[cur][irow * 72 + q8 * 8];
                bf16x8 b1 = *(const bf16x8*)&ksm[cur][irow * 72 + 32 + q8 * 8];
                f32x4 s = (f32x4){0.f, 0.f, 0.f, 0.f};
                s = MFMA(a0, b0, s);
                s = MFMA(a1, b1, s);
                int ig = i0 + it * 16 + l15;
                #pragma unroll
                for (int r = 0; r < 4; ++r) {
                    int jg = j0 + 16 * w + q8 * 4 + r;
                    float sv = s[r];
                    float e = __expf(sv * 0.125f);
                    lloc[r] += ((ig >= jg) && (sv != 0.0f)) ? e : 0.0f;
                }
            }
            __syncthreads();   // drains next-tile g2l (in flight during compute)
        }
    }
    #pragma unroll
    for (int off = 1; off < 16; off <<= 1)
        #pragma unroll
        for (int r = 0; r < 4; ++r)
            lloc[r] += __shfl_xor(lloc[r], off);
    if (l15 == 0) {
        #pragma unroll
        for (int r = 0; r < 4; ++r)
            l2[ic * 8192 + bz * kN + j0 + 16 * w + q8 * 4 + r] = lloc[r];
    }
}

// ---------------------------------------------------------------------------
// out: partial[i,h] = sum_{j in chunk, j<=i} exp(s/8)*(1/l[j])*v[j,h]
// Grid 512: b&3 = j-chunk(512), (b>>2)&3 = bz, b>>4 = i-tile(64).
// combine fused (rsm computed from l2's 4 chunks); q/v/r double-buffered.
// S recomputed with bit-identical MFMA sequence as stats.
// ---------------------------------------------------------------------------
__global__ __launch_bounds__(256) void out_kernel(
        const short* __restrict__ gq, const short* __restrict__ gk,
        const short* __restrict__ vt, const float* __restrict__ l2,
        float* __restrict__ part)
{
    __shared__ __align__(16) short ksm[64 * 72];
    __shared__ __align__(16) short qsm[2][64 * 72];
    __shared__ __align__(16) short vsm[2][64 * 72];
    __shared__ __align__(16) short psm[64 * 72];
    __shared__ float rsm[2][64];
    const int t = threadIdx.x;
    const int w = t >> 6, lane = t & 63, l15 = lane & 15, q8 = lane >> 4;
    const int b = blockIdx.x;
    const int jc = b & 3, bz = (b >> 2) & 3, it = b >> 4;
    const int i0 = it * 64;
    const int jlo = jc * 512;
    const int jhi = (jlo + 512 < i0 + 64) ? (jlo + 512) : (i0 + 64);
    const int count = (jlo < jhi) ? ((jhi - jlo) >> 6) : 0;

    f32x4 oacc[4];
    #pragma unroll
    for (int i = 0; i < 4; ++i) oacc[i] = (f32x4){0.f, 0.f, 0.f, 0.f};

    if (count > 0) {
        g2l(ksm, gk + (size_t)(bz * kN + i0) * 72, 64 * 144, t);
        g2l(qsm[0], gq + (size_t)(bz * kN + jlo) * 72, 64 * 144, t);
        g2l(vsm[0], vt + (size_t)((bz * 32 + (jlo >> 6)) * 64) * 72, 64 * 144, t);
        if (t < 64) {
            int j = bz * kN + jlo + t;
            float l = l2[j] + l2[8192 + j] + l2[16384 + j] + l2[24576 + j];
            rsm[0][t] = (l > 0.f) ? 1.0f / l : 0.0f;
        }
        __syncthreads();

        for (int idx = 0; idx < count; ++idx) {
            const int cur = idx & 1, nb = cur ^ 1;
            const int j0s = jlo + idx * 64;
            if (idx + 1 < count) {
                g2l(qsm[nb], gq + (size_t)(bz * kN + j0s + 64) * 72, 64 * 144, t);
                g2l(vsm[nb], vt + (size_t)((bz * 32 + ((j0s + 64) >> 6)) * 64) * 72,
                    64 * 144, t);
                if (t < 64) {
                    int j = bz * kN + j0s + 64 + t;
                    float l = l2[j] + l2[8192 + j] + l2[16384 + j] + l2[24576 + j];
                    rsm[nb][t] = (l > 0.f) ? 1.0f / l : 0.0f;
                }
            }
            // S phase (identical sequence to stats)
            int jrow = 16 * w + l15;
            bf16x8 a0 = *(const bf16x8*)&qsm[cur][jrow * 72 + q8 * 8];
            bf16x8 a1 = *(const bf16x8*)&qsm[cur][jrow * 72 + 32 + q8 * 8];
            #pragma unroll
            for (int itile = 0; itile < 4; ++itile) {
                int irow = itile * 16 + l15;
                bf16x8 b0 = *(const bf16x8*)&ksm[irow * 72 + q8 * 8];
                bf16x8 b1 = *(const bf16x8*)&ksm[irow * 72 + 32 + q8 * 8];
                f32x4 s = (f32x4){0.f, 0.f, 0.f, 0.f};
                s = MFMA(a0, b0, s);
                s = MFMA(a1, b1, s);
                int ig = i0 + itile * 16 + l15;
                bf16x4 pk;
                #pragma unroll
                for (int r = 0; r < 4; ++r) {
                    int jl = 16 * w + q8 * 4 + r;
                    int jg = j0s + jl;
                    float sv = s[r];
                    float p = ((ig >= jg) && (sv != 0.0f))
                            ? __expf(sv * 0.125f) * rsm[cur][jl] : 0.0f;
                    pk[r] = f2bf(p);
                }
                *(bf16x4*)&psm[(itile * 16 + l15) * 72 + 16 * w + q8 * 4] = pk;
            }
            __syncthreads();   // psm ready; next-tile g2l had S-phase to fly

            // PV phase: A = psm[i-local][j], B = vsm[h][j]
            bf16x8 pa0 = *(const bf16x8*)&psm[(16 * w + l15) * 72 + q8 * 8];
            bf16x8 pa1 = *(const bf16x8*)&psm[(16 * w + l15) * 72 + 32 + q8 * 8];
            #pragma unroll
            for (int ht = 0; ht < 4; ++ht) {
                int vrow = ht * 16 + l15;
                bf16x8 vb0 = *(const bf16x8*)&vsm[cur][vrow * 72 + q8 * 8];
                bf16x8 vb1 = *(const bf16x8*)&vsm[cur][vrow * 72 + 32 + q8 * 8];
                oacc[ht] = MFMA(pa0, vb0, oacc[ht]);
                oacc[ht] = MFMA(pa1, vb1, oacc[ht]);
            }
            __syncthreads();   // protect psm + qsm[cur]/vsm[cur] for next iter
        }
    }
    size_t base = ((size_t)(jc * 4 + bz) * kN + i0) * 64;
    #pragma unroll
    for (int ht = 0; ht < 4; ++ht)
        #pragma unroll
        for (int r = 0; r < 4; ++r)
            part[base + (size_t)(16 * w + q8 * 4 + r) * 64 + ht * 16 + l15] = oacc[ht][r];
}

// ---------------------------------------------------------------------------
// reduce: out = sum of 4 j-chunk partials
// ---------------------------------------------------------------------------
__global__ __launch_bounds__(256) void reduce_kernel(
        const float* __restrict__ part, float* __restrict__ out)
{
    int idx = blockIdx.x * 256 + threadIdx.x;     // 0..131071 float4s
    const float4* p = (const float4*)part;
    float4 a = p[idx];
    float4 b = p[idx + 131072];
    float4 c = p[idx + 262144];
    float4 d = p[idx + 393216];
    float4 r;
    r.x = a.x + b.x + c.x + d.x;
    r.y = a.y + b.y + c.y + d.y;
    r.z = a.z + b.z + c.z + d.z;
    r.w = a.w + b.w + c.w + d.w;
    ((float4*)out)[idx] = r;
}

extern "C" void kernel_launch(void* const* d_in, const int* in_sizes, int n_in,
                              void* d_out, int out_size, void* d_ws, size_t ws_size,
                              hipStream_t stream)
{
    const float* x  = (const float*)d_in[0];
    const float* Wq = (const float*)d_in[1];
    const float* bq = (const float*)d_in[2];
    const float* Wk = (const float*)d_in[3];
    const float* bk = (const float*)d_in[4];
    const float* Wv = (const float*)d_in[5];
    const float* bv = (const float*)d_in[6];
    float* out = (float*)d_out;

    char* base = (char*)d_ws;
    short* Wt   = (short*)(base);                    //    442,368 B
    float* bcat = (float*)(base + 442368);           //      1,024 B
    short* gq   = (short*)(base + 443392);           //  1,179,648 B
    short* gk   = (short*)(base + 1623040);          //  1,179,648 B
    short* vt   = (short*)(base + 2802688);          //  1,179,648 B
    float* l2   = (float*)(base + 3982336);          //    131,072 B
    float* part = (float*)(base + 4113408);          //  8,388,608 B (~12.5 MB total)

    prep_kernel<<<128, 256, 0, stream>>>(Wq, Wk, Wv, bq, bk, bv, Wt, bcat);
    qkv_kernel<<<512, 256, 0, stream>>>(x, Wt, bcat, gq, gk, vt);
    stats_kernel<<<512, 256, 0, stream>>>(gq, gk, l2);
    out_kernel<<<512, 256, 0, stream>>>(gq, gk, vt, l2, part);
    reduce_kernel<<<512, 256, 0, stream>>>(part, out);
}